// Round 15
// baseline (137.937 us; speedup 1.0000x reference)
//
#include <hip/hip_runtime.h>
#include <math.h>

// Problem constants
#define B_TOT 2048
#define S_LEN 256
#define DIN   3
#define H     128
#define DOUT  6
#define DT_C  0.1f

#define NROWS 8    // batch rows per block (R0/R5 structure: best measured)
#define PPAD  132  // f32 row stride in sh_p (head staging only)
#define XPAD  772  // f32 row stride in sh_x (768 + 4): rows on distinct banks

// scale folded into W_hh/W_xh/b_hh so epilogue uses exp2 directly:
// tanh(p) = 1 - 2/(exp2(p * 2*log2e)+1)
#define PRESCALE 2.8853900817779268f   // 2*log2(e)

typedef __attribute__((ext_vector_type(8))) short short8;
typedef __attribute__((ext_vector_type(4))) float f32x4;

// lane-pair exchange lane <-> lane^8 within 16-lane DPP row (full-rate VALU)
__device__ __forceinline__ float dpp_xor8(float v) {
  int i = __float_as_int(v);
  int r = __builtin_amdgcn_update_dpp(i, i, 0x128 /*row_ror:8*/, 0xF, 0xF, false);
  return __int_as_float(r);
}

// HW RNE f32x2 -> packed bf16x2 (validated R2/R3: absmax identical to SW pack)
__device__ __forceinline__ unsigned int cvt_pk_bf16(float a, float b) {
  unsigned int r;
  asm("v_cvt_pk_bf16_f32 %0, %1, %2" : "=v"(r) : "v"(a), "v"(b));
  return r;
}

// R6 = R5 (81.5us, 764cy/step measured) + R3's conflict-free pre-swizzled
// h-exchange layout, ISOLATED from R3's asm barrier (kept plain __syncthreads).
// R5's row-major layout: rd banks 4*(l16+quad) mod 32 -> 4-way conflicts,
// 4.19M conflict-cycles = 64 cy/CU-step queued right after the barrier,
// on the critical path before the first MFMA.
//
// h layout (R3-verified numerics, 0 conflicts measured there):
//   16B slot (kc,quad,b) = kc*32 + quad*8 + b  holds h[b][kc*32+quad*8 .. +8]
//   Read: lane (quad,l16<8) reads slot kc*32+quad*8+l16 -> 32 active lanes
//   read 32 CONSECUTIVE slots per kc: peak-rate burst, zero conflicts.
//   Write: lane owns (brow=l16&7, j0, j0+1) -> shorts i'=(j0&7), i'+1 of slot
//   ((j0>>5), (j0>>3)&3, brow); bank = brow*4+(quad&1)*2+(l16>>3): 32 banks
//   x 2 lanes = 2-way, free.
// All else byte-identical to R5: x fully LDS-staged (no vmem in loop ->
// barrier vmcnt drain free), 2x2 MFMA chains, masked B-frag reads, DPP
// epilogue, one __syncthreads per step.
__launch_bounds__(512, 2)
__global__ void ltc_kernel(const float* __restrict__ x,
                           const float* __restrict__ W_xh,
                           const float* __restrict__ W_hh,
                           const float* __restrict__ b_hh,
                           const float* __restrict__ log_tau,
                           const float* __restrict__ fc_W,
                           const float* __restrict__ fc_b,
                           float* __restrict__ out) {
  __shared__ alignas(16) unsigned short sh_h[2][1024];  // ping-pong h bf16, 2KB each
  __shared__ alignas(16) float sh_x[NROWS][XPAD];       // whole x tile (24KB)
  __shared__ alignas(16) float sh_p[NROWS][PPAD];       // final h fp32 for head

  const int tid  = threadIdx.x;
  const int w    = tid >> 6;        // wave 0..7 -> j-tile [w*16, w*16+16)
  const int lane = tid & 63;
  const int quad = lane >> 4;       // 0..3
  const int l16  = lane & 15;       // b-column in B/D fragments
  const int rb0  = blockIdx.x * NROWS;

  // ---- zero both h buffers ----
  {
    uint4* p = (uint4*)&sh_h[0][0];
    for (int i = tid; i < 256; i += 512) p[i] = make_uint4(0, 0, 0, 0);
  }

  // ---- stage x for the block's 8 rows into LDS (768 f32/row, pad to 772) ----
  {
    const float* srcx = x + (size_t)rb0 * (S_LEN * DIN);
    for (int i = tid; i < NROWS * 192; i += 512) {
      const int r  = i / 192;
      const int c4 = i - r * 192;
      *(float4*)&sh_x[r][c4 * 4] =
          *(const float4*)(srcx + (size_t)r * (S_LEN * DIN) + c4 * 4);
    }
  }

  // ---- W_hh A-fragments (PRESCALE*W, RNE bf16), register-resident ----
  // A[m=l16][k = kc*32 + quad*8 + i],  j = w*16 + m
  short8 wa[4];
  {
    const int jj = w * 16 + l16;
#pragma unroll
    for (int kc = 0; kc < 4; ++kc) {
      const float* src = W_hh + jj * H + kc * 32 + quad * 8;
#pragma unroll
      for (int i = 0; i < 8; ++i)
        wa[kc][i] = (short)(cvt_pk_bf16(src[i] * PRESCALE, 0.f) & 0xFFFFu);
    }
  }

  // ---- dense epilogue mapping: lane owns (b=l16&7, j0=w*16+quad*4+(l16>>3)*2+{0,1}) ----
  const int brow = l16 & 7;
  const int rbse = (l16 >> 3) * 2;            // 0 for lanes b, 2 for partners b+8
  const int j0   = w * 16 + quad * 4 + rbse;
  float ewx[2][3], ebh[2], ecc[2], ea[2], encc2[2];
#pragma unroll
  for (int r = 0; r < 2; ++r) {
    const int j = j0 + r;
    ewx[r][0] = W_xh[j * 3 + 0] * PRESCALE;
    ewx[r][1] = W_xh[j * 3 + 1] * PRESCALE;
    ewx[r][2] = W_xh[j * 3 + 2] * PRESCALE;
    ebh[r]    = b_hh[j] * PRESCALE;
    float lt  = log_tau[j];
    float tau = logf(1.f + expf(lt)) + 0.001f;   // softplus + eps, exact fp32
    float cc  = DT_C / tau;
    ecc[r]    = cc;
    ea[r]     = 1.f - cc;
    encc2[r]  = -2.f * cc;
  }
  const bool lowhalf = (l16 < 8);

  float hreg[2] = {0.f, 0.f};  // fp32 h for (brow, j0..j0+1), register-resident

  // static LDS offsets (shorts) — pre-swizzled B-fragment-order layout
  const int rd_off = quad * 64 + l16 * 8;   // + kc*256; l16<8: 32 consecutive slots
  const int wr_off = (j0 >> 5) * 256 + ((j0 >> 3) & 3) * 64 + brow * 8 + (j0 & 7);
  const unsigned short* __restrict__ buf0 = &sh_h[0][0];
  unsigned short* __restrict__ buf1 = &sh_h[1][0];

  // persistent B-frag regs: zeroed ONCE; lanes l16>=8 never overwrite them
  short8 bf[4];
#pragma unroll
  for (int kc = 0; kc < 4; ++kc) bf[kc] = short8{0, 0, 0, 0, 0, 0, 0, 0};

  __syncthreads();   // sh_h zeroed + sh_x staged visible to all waves

  // ---- x prefetch from LDS: 6 floats per 2-step pair, 1 pair ahead ----
  const float* xrow = &sh_x[brow][0];
  float2 pfa = *(const float2*)(xrow);
  float2 pfb = *(const float2*)(xrow + 2);
  float2 pfc = *(const float2*)(xrow + 4);
  const float* xq = xrow + 6;

  auto do_step = [&](const unsigned short* __restrict__ cur,
                     unsigned short* __restrict__ nxt,
                     float xc0, float xc1, float xc2) {
    // B-fragments of h^T (masked; lanes l16>=8 keep zeros).
    // 32 active lanes read 32 consecutive 16B slots per kc: conflict-free.
    if (l16 < NROWS) {
#pragma unroll
      for (int kc = 0; kc < 4; ++kc)
        bf[kc] = *(const short8*)(cur + rd_off + kc * 256);
    }

    // x-projection terms for this lane's 2 elems (issue under ds_read shadow)
    float t0 = __builtin_fmaf(xc2, ewx[0][2], ebh[0]);
    t0 = __builtin_fmaf(xc1, ewx[0][1], t0);
    t0 = __builtin_fmaf(xc0, ewx[0][0], t0);
    float t1 = __builtin_fmaf(xc2, ewx[1][2], ebh[1]);
    t1 = __builtin_fmaf(xc1, ewx[1][1], t1);
    t1 = __builtin_fmaf(xc0, ewx[1][0], t1);

    // two independent 2-deep MFMA chains + elementwise add (R2/R3-validated)
    f32x4 a0 = {0.f, 0.f, 0.f, 0.f};
    f32x4 a1 = {0.f, 0.f, 0.f, 0.f};
    a0 = __builtin_amdgcn_mfma_f32_16x16x32_bf16(wa[0], bf[0], a0, 0, 0, 0);
    a1 = __builtin_amdgcn_mfma_f32_16x16x32_bf16(wa[2], bf[2], a1, 0, 0, 0);
    a0 = __builtin_amdgcn_mfma_f32_16x16x32_bf16(wa[1], bf[1], a0, 0, 0, 0);
    a1 = __builtin_amdgcn_mfma_f32_16x16x32_bf16(wa[3], bf[3], a1, 0, 0, 0);

    const float d0 = a0[0] + a1[0];
    const float d1 = a0[1] + a1[1];
    const float d2 = a0[2] + a1[2];
    const float d3 = a0[3] + a1[3];

    // DPP pair-exchange: partner lanes (l16>=8) receive r=2,3 from lane l16-8
    float e2 = dpp_xor8(d2);
    float e3 = dpp_xor8(d3);
    float pre0 = lowhalf ? d0 : e2;
    float pre1 = lowhalf ? d1 : e3;

    // dense epilogue: 2 elems/lane, every lane
    {
      float e  = __builtin_amdgcn_exp2f(pre0 + t0);
      float rc = __builtin_amdgcn_rcpf(e + 1.f);
      hreg[0] = __builtin_fmaf(encc2[0], rc, __builtin_fmaf(hreg[0], ea[0], ecc[0]));
    }
    {
      float e  = __builtin_amdgcn_exp2f(pre1 + t1);
      float rc = __builtin_amdgcn_rcpf(e + 1.f);
      hreg[1] = __builtin_fmaf(encc2[1], rc, __builtin_fmaf(hreg[1], ea[1], ecc[1]));
    }

    // dense 4B store into the pre-swizzled layout (2-way bank, free)
    *(unsigned int*)(nxt + wr_off) = cvt_pk_bf16(hreg[0], hreg[1]);
    __syncthreads();   // vmcnt(0) part is free: no vmem ops in the loop
  };

  for (int s = 0; s < S_LEN; s += 2) {
    float2 xa = pfa, xb = pfb, xc = pfc;
    if (s + 2 < S_LEN) {             // uniform branch; prefetch next pair (LDS)
      pfa = *(const float2*)(xq);
      pfb = *(const float2*)(xq + 2);
      pfc = *(const float2*)(xq + 4);
      xq += 6;
    }
    do_step(buf0, buf1, xa.x, xa.y, xb.x);
    do_step(buf1, (unsigned short*)buf0, xb.y, xc.x, xc.y);
  }

  // ---- final head: params = softplus(h @ fc_W^T + fc_b), [8 x 6] per block ----
  {
    float2 v = make_float2(hreg[0], hreg[1]);
    *(float2*)&sh_p[brow][j0] = v;   // 8B-aligned (j0 even), all lanes distinct
  }
  __syncthreads();

  if (tid < NROWS * DOUT) {
    const int b = tid / DOUT;
    const int o = tid - b * DOUT;
    const float* fw = fc_W + o * H;
    float acc = fc_b[o];
#pragma unroll 4
    for (int k = 0; k < H; ++k) acc += sh_p[b][k] * fw[k];
    float sp = (acc > 15.f) ? acc : logf(1.f + expf(acc));
    out[(rb0 + b) * DOUT + o] = sp;
  }
}

extern "C" void kernel_launch(void* const* d_in, const int* in_sizes, int n_in,
                              void* d_out, int out_size, void* d_ws, size_t ws_size,
                              hipStream_t stream) {
  const float* x       = (const float*)d_in[0];
  const float* W_xh    = (const float*)d_in[1];
  const float* W_hh    = (const float*)d_in[2];
  const float* b_hh    = (const float*)d_in[3];
  const float* log_tau = (const float*)d_in[4];
  const float* fc_W    = (const float*)d_in[5];
  const float* fc_b    = (const float*)d_in[6];
  float* out           = (float*)d_out;

  ltc_kernel<<<dim3(B_TOT / NROWS), dim3(512), 0, stream>>>(
      x, W_xh, W_hh, b_hh, log_tau, fc_W, fc_b, out);
}

// Round 16
// 134.132 us; speedup vs baseline: 1.0284x; 1.0284x over previous
//
#include <hip/hip_runtime.h>
#include <math.h>

// Problem constants
#define B_TOT 2048
#define S_LEN 256
#define DIN   3
#define H     128
#define DOUT  6
#define DT_C  0.1f

#define NROWS 8    // batch rows per block (R0/R5 structure: best measured)
#define PPAD  132  // f32 row stride in sh_p (head staging only)
#define XPAD  772  // f32 row stride in sh_x (768 + 4): rows on distinct banks

// scale folded into W_hh/W_xh/b_hh so epilogue uses exp2 directly:
// tanh(p) = 1 - 2/(exp2(p * 2*log2e)+1)
#define PRESCALE 2.8853900817779268f   // 2*log2(e)

typedef __attribute__((ext_vector_type(8))) short short8;
typedef __attribute__((ext_vector_type(4))) float f32x4;

// HW RNE f32x2 -> packed bf16x2 (validated R2/R3: absmax identical to SW pack)
__device__ __forceinline__ unsigned int cvt_pk_bf16(float a, float b) {
  unsigned int r;
  asm("v_cvt_pk_bf16_f32 %0, %1, %2" : "=v"(r) : "v"(a), "v"(b));
  return r;
}

// R7 = R6 (81.4us, 764cy/step, 0 bank conflicts) + broadcast B-frag read
// (R2-validated): ALL 64 lanes read slot (kc,quad,l16&7) -> lanes 8-15
// duplicate lanes 0-7's B columns (same-address LDS broadcast, free), so
// D cols 8-15 are bit-exact copies of cols 0-7. Partner lanes then use their
// OWN d2,d3 in the epilogue: removes the exec-mask branch, the 2 DPP
// exchanges, the 2 persistent-zero B-frag registers -- ~8-10 instructions
// off the serial per-step chain.
//
// Carried from R5/R6 (all measured):
//  - x staged entirely in LDS at prologue: zero vmem in the loop, so
//    __syncthreads()'s vmcnt(0) drain is free (R5: -106cy/step).
//  - pre-swizzled B-fragment-order h layout: 32 consecutive 16B slots per
//    kc read burst, 0 bank conflicts (R6; free, kept for robustness).
//  - 2x2 independent MFMA chains + adds (R5).
//  - plain __syncthreads() (R3: asm barrier defeats scheduling, +380cy).
// One barrier/step; ping-pong h buffers; dense 2-elem/lane epilogue.
__launch_bounds__(512, 2)
__global__ void ltc_kernel(const float* __restrict__ x,
                           const float* __restrict__ W_xh,
                           const float* __restrict__ W_hh,
                           const float* __restrict__ b_hh,
                           const float* __restrict__ log_tau,
                           const float* __restrict__ fc_W,
                           const float* __restrict__ fc_b,
                           float* __restrict__ out) {
  __shared__ alignas(16) unsigned short sh_h[2][1024];  // ping-pong h bf16, 2KB each
  __shared__ alignas(16) float sh_x[NROWS][XPAD];       // whole x tile (24KB)
  __shared__ alignas(16) float sh_p[NROWS][PPAD];       // final h fp32 for head

  const int tid  = threadIdx.x;
  const int w    = tid >> 6;        // wave 0..7 -> j-tile [w*16, w*16+16)
  const int lane = tid & 63;
  const int quad = lane >> 4;       // 0..3
  const int l16  = lane & 15;       // b-column in B/D fragments
  const int rb0  = blockIdx.x * NROWS;

  // ---- zero both h buffers ----
  {
    uint4* p = (uint4*)&sh_h[0][0];
    for (int i = tid; i < 256; i += 512) p[i] = make_uint4(0, 0, 0, 0);
  }

  // ---- stage x for the block's 8 rows into LDS (768 f32/row, pad to 772) ----
  {
    const float* srcx = x + (size_t)rb0 * (S_LEN * DIN);
    for (int i = tid; i < NROWS * 192; i += 512) {
      const int r  = i / 192;
      const int c4 = i - r * 192;
      *(float4*)&sh_x[r][c4 * 4] =
          *(const float4*)(srcx + (size_t)r * (S_LEN * DIN) + c4 * 4);
    }
  }

  // ---- W_hh A-fragments (PRESCALE*W, RNE bf16), register-resident ----
  // A[m=l16][k = kc*32 + quad*8 + i],  j = w*16 + m
  short8 wa[4];
  {
    const int jj = w * 16 + l16;
#pragma unroll
    for (int kc = 0; kc < 4; ++kc) {
      const float* src = W_hh + jj * H + kc * 32 + quad * 8;
#pragma unroll
      for (int i = 0; i < 8; ++i)
        wa[kc][i] = (short)(cvt_pk_bf16(src[i] * PRESCALE, 0.f) & 0xFFFFu);
    }
  }

  // ---- dense epilogue mapping: lane owns (b=l16&7, j0=w*16+quad*4+(l16>>3)*2+{0,1}) ----
  const int brow = l16 & 7;
  const int rbse = (l16 >> 3) * 2;            // 0 for lanes b, 2 for partners b+8
  const int j0   = w * 16 + quad * 4 + rbse;
  float ewx[2][3], ebh[2], ecc[2], ea[2], encc2[2];
#pragma unroll
  for (int r = 0; r < 2; ++r) {
    const int j = j0 + r;
    ewx[r][0] = W_xh[j * 3 + 0] * PRESCALE;
    ewx[r][1] = W_xh[j * 3 + 1] * PRESCALE;
    ewx[r][2] = W_xh[j * 3 + 2] * PRESCALE;
    ebh[r]    = b_hh[j] * PRESCALE;
    float lt  = log_tau[j];
    float tau = logf(1.f + expf(lt)) + 0.001f;   // softplus + eps, exact fp32
    float cc  = DT_C / tau;
    ecc[r]    = cc;
    ea[r]     = 1.f - cc;
    encc2[r]  = -2.f * cc;
  }
  const bool lowhalf = (l16 < 8);

  float hreg[2] = {0.f, 0.f};  // fp32 h for (brow, j0..j0+1), register-resident

  // static LDS offsets (shorts) — pre-swizzled B-fragment-order layout.
  // BROADCAST read: all 64 lanes; lanes l16>=8 duplicate lanes l16-8
  // (same-address broadcast, free). 32 distinct consecutive slots per kc.
  const int rd_off = quad * 64 + brow * 8;  // + kc*256
  const int wr_off = (j0 >> 5) * 256 + ((j0 >> 3) & 3) * 64 + brow * 8 + (j0 & 7);
  const unsigned short* __restrict__ buf0 = &sh_h[0][0];
  unsigned short* __restrict__ buf1 = &sh_h[1][0];

  __syncthreads();   // sh_h zeroed + sh_x staged visible to all waves

  // ---- x prefetch from LDS: 6 floats per 2-step pair, 1 pair ahead ----
  const float* xrow = &sh_x[brow][0];
  float2 pfa = *(const float2*)(xrow);
  float2 pfb = *(const float2*)(xrow + 2);
  float2 pfc = *(const float2*)(xrow + 4);
  const float* xq = xrow + 6;

  auto do_step = [&](const unsigned short* __restrict__ cur,
                     unsigned short* __restrict__ nxt,
                     float xc0, float xc1, float xc2) {
    // B-fragments of h^T: unmasked broadcast read (cols 8-15 dup cols 0-7)
    short8 b0 = *(const short8*)(cur + rd_off);
    short8 b1 = *(const short8*)(cur + rd_off + 256);
    short8 b2 = *(const short8*)(cur + rd_off + 512);
    short8 b3 = *(const short8*)(cur + rd_off + 768);

    // x-projection terms for this lane's 2 elems (issue under ds_read shadow)
    float t0 = __builtin_fmaf(xc2, ewx[0][2], ebh[0]);
    t0 = __builtin_fmaf(xc1, ewx[0][1], t0);
    t0 = __builtin_fmaf(xc0, ewx[0][0], t0);
    float t1 = __builtin_fmaf(xc2, ewx[1][2], ebh[1]);
    t1 = __builtin_fmaf(xc1, ewx[1][1], t1);
    t1 = __builtin_fmaf(xc0, ewx[1][0], t1);

    // two independent 2-deep MFMA chains + elementwise add (R2/R3-validated)
    f32x4 a0 = {0.f, 0.f, 0.f, 0.f};
    f32x4 a1 = {0.f, 0.f, 0.f, 0.f};
    a0 = __builtin_amdgcn_mfma_f32_16x16x32_bf16(wa[0], b0, a0, 0, 0, 0);
    a1 = __builtin_amdgcn_mfma_f32_16x16x32_bf16(wa[2], b2, a1, 0, 0, 0);
    a0 = __builtin_amdgcn_mfma_f32_16x16x32_bf16(wa[1], b1, a0, 0, 0, 0);
    a1 = __builtin_amdgcn_mfma_f32_16x16x32_bf16(wa[3], b3, a1, 0, 0, 0);

    // lanes l16>=8 hold bit-identical D to lanes l16-8 (duplicated B cols):
    // partner lanes take their OWN r=2,3 — no DPP exchange needed.
    const float d0 = a0[0] + a1[0];
    const float d1 = a0[1] + a1[1];
    const float d2 = a0[2] + a1[2];
    const float d3 = a0[3] + a1[3];
    float pre0 = lowhalf ? d0 : d2;
    float pre1 = lowhalf ? d1 : d3;

    // dense epilogue: 2 elems/lane, every lane
    {
      float e  = __builtin_amdgcn_exp2f(pre0 + t0);
      float rc = __builtin_amdgcn_rcpf(e + 1.f);
      hreg[0] = __builtin_fmaf(encc2[0], rc, __builtin_fmaf(hreg[0], ea[0], ecc[0]));
    }
    {
      float e  = __builtin_amdgcn_exp2f(pre1 + t1);
      float rc = __builtin_amdgcn_rcpf(e + 1.f);
      hreg[1] = __builtin_fmaf(encc2[1], rc, __builtin_fmaf(hreg[1], ea[1], ecc[1]));
    }

    // dense 4B store into the pre-swizzled layout (2-way bank, free)
    *(unsigned int*)(nxt + wr_off) = cvt_pk_bf16(hreg[0], hreg[1]);
    __syncthreads();   // vmcnt(0) part is free: no vmem ops in the loop
  };

  for (int s = 0; s < S_LEN; s += 2) {
    float2 xa = pfa, xb = pfb, xc = pfc;
    if (s + 2 < S_LEN) {             // uniform branch; prefetch next pair (LDS)
      pfa = *(const float2*)(xq);
      pfb = *(const float2*)(xq + 2);
      pfc = *(const float2*)(xq + 4);
      xq += 6;
    }
    do_step(buf0, buf1, xa.x, xa.y, xb.x);
    do_step(buf1, (unsigned short*)buf0, xb.y, xc.x, xc.y);
  }

  // ---- final head: params = softplus(h @ fc_W^T + fc_b), [8 x 6] per block ----
  {
    float2 v = make_float2(hreg[0], hreg[1]);
    *(float2*)&sh_p[brow][j0] = v;   // 8B-aligned (j0 even), all lanes distinct
  }
  __syncthreads();

  if (tid < NROWS * DOUT) {
    const int b = tid / DOUT;
    const int o = tid - b * DOUT;
    const float* fw = fc_W + o * H;
    float acc = fc_b[o];
#pragma unroll 4
    for (int k = 0; k < H; ++k) acc += sh_p[b][k] * fw[k];
    float sp = (acc > 15.f) ? acc : logf(1.f + expf(acc));
    out[(rb0 + b) * DOUT + o] = sp;
  }
}

extern "C" void kernel_launch(void* const* d_in, const int* in_sizes, int n_in,
                              void* d_out, int out_size, void* d_ws, size_t ws_size,
                              hipStream_t stream) {
  const float* x       = (const float*)d_in[0];
  const float* W_xh    = (const float*)d_in[1];
  const float* W_hh    = (const float*)d_in[2];
  const float* b_hh    = (const float*)d_in[3];
  const float* log_tau = (const float*)d_in[4];
  const float* fc_W    = (const float*)d_in[5];
  const float* fc_b    = (const float*)d_in[6];
  float* out           = (float*)d_out;

  ltc_kernel<<<dim3(B_TOT / NROWS), dim3(512), 0, stream>>>(
      x, W_xh, W_hh, b_hh, log_tau, fc_W, fc_b, out);
}

// Round 17
// 128.081 us; speedup vs baseline: 1.0769x; 1.0472x over previous
//
#include <hip/hip_runtime.h>
#include <math.h>

// Problem constants
#define B_TOT 2048
#define S_LEN 256
#define DIN   3
#define H     128
#define DOUT  6
#define DT_C  0.1f

#define NROWS 8    // batch rows per block (locked: grid 256 = 1 block/CU exact)
#define PPAD  132  // f32 row stride in sh_p (head staging only)
#define XPAD  780  // f32 row stride in sh_x (768+12): distinct row banks, +6 over-read pad

// scale folded into W_hh/W_xh/b_hh so epilogue uses exp2 directly:
// tanh(p) = 1 - 2/(exp2(p * 2*log2e)+1)
#define PRESCALE 2.8853900817779268f   // 2*log2(e)

typedef __attribute__((ext_vector_type(8))) short short8;
typedef __attribute__((ext_vector_type(4))) float f32x4;

// HW RNE f32x2 -> packed bf16x2 (validated R2/R3: absmax identical to SW pack)
__device__ __forceinline__ unsigned int cvt_pk_bf16(float a, float b) {
  unsigned int r;
  asm("v_cvt_pk_bf16_f32 %0, %1, %2" : "=v"(r) : "v"(a), "v"(b));
  return r;
}

// R8 = R7 (79.6us, ~746cy/step) + issue-count polish, arithmetic unchanged:
//  (1) x-projection t-FMAs hoisted BEFORE each pair's first step: the 12 FMAs
//      overlap the previous step's stall instead of the post-ds_read window.
//  (2) 4-step unroll (64 iters): half the loop-control ops per step.
//  (3) branchless prefetch: XPAD 780 lets the final (dead) pair-load read
//      safe in-bounds junk -- no per-pair uniform branch.
// Carried (all measured): x fully LDS-staged (R5: no loop vmem -> barrier
// vmcnt drain free, -106cy); pre-swizzled conflict-free h layout (R6: 0
// conflicts); broadcast B-read, no masks/DPP (R7: -18cy); 2x2 MFMA chains
// (R5); plain __syncthreads (R3: asm barrier +380cy).
__launch_bounds__(512, 2)
__global__ void ltc_kernel(const float* __restrict__ x,
                           const float* __restrict__ W_xh,
                           const float* __restrict__ W_hh,
                           const float* __restrict__ b_hh,
                           const float* __restrict__ log_tau,
                           const float* __restrict__ fc_W,
                           const float* __restrict__ fc_b,
                           float* __restrict__ out) {
  __shared__ alignas(16) unsigned short sh_h[2][1024];  // ping-pong h bf16, 2KB each
  __shared__ alignas(16) float sh_x[NROWS][XPAD];       // whole x tile (~24KB)
  __shared__ alignas(16) float sh_p[NROWS][PPAD];       // final h fp32 for head

  const int tid  = threadIdx.x;
  const int w    = tid >> 6;        // wave 0..7 -> j-tile [w*16, w*16+16)
  const int lane = tid & 63;
  const int quad = lane >> 4;       // 0..3
  const int l16  = lane & 15;       // b-column in B/D fragments
  const int rb0  = blockIdx.x * NROWS;

  // ---- zero both h buffers ----
  {
    uint4* p = (uint4*)&sh_h[0][0];
    for (int i = tid; i < 256; i += 512) p[i] = make_uint4(0, 0, 0, 0);
  }

  // ---- stage x for the block's 8 rows into LDS (768 f32/row) ----
  {
    const float* srcx = x + (size_t)rb0 * (S_LEN * DIN);
    for (int i = tid; i < NROWS * 192; i += 512) {
      const int r  = i / 192;
      const int c4 = i - r * 192;
      *(float4*)&sh_x[r][c4 * 4] =
          *(const float4*)(srcx + (size_t)r * (S_LEN * DIN) + c4 * 4);
    }
  }

  // ---- W_hh A-fragments (PRESCALE*W, RNE bf16), register-resident ----
  // A[m=l16][k = kc*32 + quad*8 + i],  j = w*16 + m
  short8 wa[4];
  {
    const int jj = w * 16 + l16;
#pragma unroll
    for (int kc = 0; kc < 4; ++kc) {
      const float* src = W_hh + jj * H + kc * 32 + quad * 8;
#pragma unroll
      for (int i = 0; i < 8; ++i)
        wa[kc][i] = (short)(cvt_pk_bf16(src[i] * PRESCALE, 0.f) & 0xFFFFu);
    }
  }

  // ---- dense epilogue mapping: lane owns (b=l16&7, j0=w*16+quad*4+(l16>>3)*2+{0,1}) ----
  const int brow = l16 & 7;
  const int rbse = (l16 >> 3) * 2;            // 0 for lanes b, 2 for partners b+8
  const int j0   = w * 16 + quad * 4 + rbse;
  float ewx[2][3], ebh[2], ecc[2], ea[2], encc2[2];
#pragma unroll
  for (int r = 0; r < 2; ++r) {
    const int j = j0 + r;
    ewx[r][0] = W_xh[j * 3 + 0] * PRESCALE;
    ewx[r][1] = W_xh[j * 3 + 1] * PRESCALE;
    ewx[r][2] = W_xh[j * 3 + 2] * PRESCALE;
    ebh[r]    = b_hh[j] * PRESCALE;
    float lt  = log_tau[j];
    float tau = logf(1.f + expf(lt)) + 0.001f;   // softplus + eps, exact fp32
    float cc  = DT_C / tau;
    ecc[r]    = cc;
    ea[r]     = 1.f - cc;
    encc2[r]  = -2.f * cc;
  }
  const bool lowhalf = (l16 < 8);

  float hreg[2] = {0.f, 0.f};  // fp32 h for (brow, j0..j0+1), register-resident

  // static LDS offsets (shorts) — pre-swizzled B-fragment-order layout.
  // BROADCAST read: lanes l16>=8 duplicate lanes l16-8 (same-address, free).
  const int rd_off = quad * 64 + brow * 8;  // + kc*256
  const int wr_off = (j0 >> 5) * 256 + ((j0 >> 3) & 3) * 64 + brow * 8 + (j0 & 7);
  const unsigned short* __restrict__ buf0 = &sh_h[0][0];
  unsigned short* __restrict__ buf1 = &sh_h[1][0];

  __syncthreads();   // sh_h zeroed + sh_x staged visible to all waves

  // x-projection terms for one step (same FMA order as R5-R7: bit-identical)
  auto compute_t = [&](float xc0, float xc1, float xc2, float& t0, float& t1) {
    t0 = __builtin_fmaf(xc2, ewx[0][2], ebh[0]);
    t0 = __builtin_fmaf(xc1, ewx[0][1], t0);
    t0 = __builtin_fmaf(xc0, ewx[0][0], t0);
    t1 = __builtin_fmaf(xc2, ewx[1][2], ebh[1]);
    t1 = __builtin_fmaf(xc1, ewx[1][1], t1);
    t1 = __builtin_fmaf(xc0, ewx[1][0], t1);
  };

  auto do_step = [&](const unsigned short* __restrict__ cur,
                     unsigned short* __restrict__ nxt,
                     float t0, float t1) {
    // B-fragments of h^T: unmasked broadcast read (cols 8-15 dup cols 0-7)
    short8 b0 = *(const short8*)(cur + rd_off);
    short8 b1 = *(const short8*)(cur + rd_off + 256);
    short8 b2 = *(const short8*)(cur + rd_off + 512);
    short8 b3 = *(const short8*)(cur + rd_off + 768);

    // two independent 2-deep MFMA chains + elementwise add
    f32x4 a0 = {0.f, 0.f, 0.f, 0.f};
    f32x4 a1 = {0.f, 0.f, 0.f, 0.f};
    a0 = __builtin_amdgcn_mfma_f32_16x16x32_bf16(wa[0], b0, a0, 0, 0, 0);
    a1 = __builtin_amdgcn_mfma_f32_16x16x32_bf16(wa[2], b2, a1, 0, 0, 0);
    a0 = __builtin_amdgcn_mfma_f32_16x16x32_bf16(wa[1], b1, a0, 0, 0, 0);
    a1 = __builtin_amdgcn_mfma_f32_16x16x32_bf16(wa[3], b3, a1, 0, 0, 0);

    // lanes l16>=8 hold bit-identical D to lanes l16-8 (duplicated B cols)
    const float d0 = a0[0] + a1[0];
    const float d1 = a0[1] + a1[1];
    const float d2 = a0[2] + a1[2];
    const float d3 = a0[3] + a1[3];
    float pre0 = lowhalf ? d0 : d2;
    float pre1 = lowhalf ? d1 : d3;

    // dense epilogue: 2 elems/lane, every lane
    {
      float e  = __builtin_amdgcn_exp2f(pre0 + t0);
      float rc = __builtin_amdgcn_rcpf(e + 1.f);
      hreg[0] = __builtin_fmaf(encc2[0], rc, __builtin_fmaf(hreg[0], ea[0], ecc[0]));
    }
    {
      float e  = __builtin_amdgcn_exp2f(pre1 + t1);
      float rc = __builtin_amdgcn_rcpf(e + 1.f);
      hreg[1] = __builtin_fmaf(encc2[1], rc, __builtin_fmaf(hreg[1], ea[1], ecc[1]));
    }

    // dense 4B store into the pre-swizzled layout (2-way bank, free)
    *(unsigned int*)(nxt + wr_off) = cvt_pk_bf16(hreg[0], hreg[1]);
    __syncthreads();   // vmcnt(0) part is free: no vmem ops in the loop
  };

  // ---- main loop: 4 steps (2 pairs) per iteration, branchless prefetch ----
  const float* xrow = &sh_x[brow][0];
  float2 A0 = *(const float2*)(xrow);
  float2 B0 = *(const float2*)(xrow + 2);
  float2 C0 = *(const float2*)(xrow + 4);
  const float* xq = xrow + 6;

  for (int it = 0; it < S_LEN / 4; ++it) {
    // prefetch pair P1 (steps 4it+2, 4it+3)
    float2 A1 = *(const float2*)(xq);
    float2 B1 = *(const float2*)(xq + 2);
    float2 C1 = *(const float2*)(xq + 4);

    float ta0, ta1, tb0, tb1;
    compute_t(A0.x, A0.y, B0.x, ta0, ta1);
    compute_t(B0.y, C0.x, C0.y, tb0, tb1);
    do_step(buf0, buf1, ta0, ta1);
    do_step(buf1, (unsigned short*)buf0, tb0, tb1);

    // prefetch pair P2 (next iteration's P0); final read is dead in-bounds junk
    A0 = *(const float2*)(xq + 6);
    B0 = *(const float2*)(xq + 8);
    C0 = *(const float2*)(xq + 10);
    xq += 12;

    compute_t(A1.x, A1.y, B1.x, ta0, ta1);
    compute_t(B1.y, C1.x, C1.y, tb0, tb1);
    do_step(buf0, buf1, ta0, ta1);
    do_step(buf1, (unsigned short*)buf0, tb0, tb1);
  }

  // ---- final head: params = softplus(h @ fc_W^T + fc_b), [8 x 6] per block ----
  {
    float2 v = make_float2(hreg[0], hreg[1]);
    *(float2*)&sh_p[brow][j0] = v;   // 8B-aligned (j0 even), all lanes distinct
  }
  __syncthreads();

  if (tid < NROWS * DOUT) {
    const int b = tid / DOUT;
    const int o = tid - b * DOUT;
    const float* fw = fc_W + o * H;
    float acc = fc_b[o];
#pragma unroll 4
    for (int k = 0; k < H; ++k) acc += sh_p[b][k] * fw[k];
    float sp = (acc > 15.f) ? acc : logf(1.f + expf(acc));
    out[(rb0 + b) * DOUT + o] = sp;
  }
}

extern "C" void kernel_launch(void* const* d_in, const int* in_sizes, int n_in,
                              void* d_out, int out_size, void* d_ws, size_t ws_size,
                              hipStream_t stream) {
  const float* x       = (const float*)d_in[0];
  const float* W_xh    = (const float*)d_in[1];
  const float* W_hh    = (const float*)d_in[2];
  const float* b_hh    = (const float*)d_in[3];
  const float* log_tau = (const float*)d_in[4];
  const float* fc_W    = (const float*)d_in[5];
  const float* fc_b    = (const float*)d_in[6];
  float* out           = (float*)d_out;

  ltc_kernel<<<dim3(B_TOT / NROWS), dim3(512), 0, stream>>>(
      x, W_xh, W_hh, b_hh, log_tau, fc_W, fc_b, out);
}